// Round 4
// baseline (558.264 us; speedup 1.0000x reference)
//
#include <hip/hip_runtime.h>
#include <hip/hip_bf16.h>

#define D 8196
#define H 4096
#define MLP_HID 32
#define OUT_N 130

__device__ __forceinline__ float sigmoidf_(float v) {
    return 1.0f / (1.0f + expf(-v));
}

__device__ __forceinline__ float dot4(float4 a, float4 b) {
    return a.x * b.x + a.y * b.y + a.z * b.z + a.w * b.w;
}

__device__ __forceinline__ float wave_reduce(float acc) {
    #pragma unroll
    for (int off = 32; off > 0; off >>= 1)
        acc += __shfl_down(acc, off);
    return acc;
}

// 2048 blocks x 256 threads. Block b owns hidden units j0=2b, j0+1.
// Wave g (0..3) computes gate rows g*H+j0 and g*H+j0+1 (one x/h0 load
// amortized over two weight rows). Plain float4 loads (nontemporal `nt`
// collapsed BW to 9% of peak on gfx950 — reverted). Last block (atomic
// counter) runs the MLP head after a device fence.
__global__ __launch_bounds__(256) void brain_fused_kernel(
    const float* __restrict__ x, const float* __restrict__ h0,
    const float* __restrict__ c0,
    const float* __restrict__ W_ih, const float* __restrict__ W_hh,
    const float* __restrict__ b_ih, const float* __restrict__ b_hh,
    const float* __restrict__ W1, const float* __restrict__ b1,
    const float* __restrict__ W2, const float* __restrict__ b2,
    float* __restrict__ out,
    unsigned int* __restrict__ counter, float* __restrict__ h_ws)
{
    const int g    = threadIdx.x >> 6;   // gate 0..3 (i,f,g,o)
    const int lane = threadIdx.x & 63;
    const int j0   = blockIdx.x * 2;
    const size_t r0 = (size_t)g * H + j0;

    float acc0 = 0.0f, acc1 = 0.0f;

    // ---- W_ih rows r0, r0+1 . x   (D/4 = 2049 float4s per row) ----
    {
        const float4* __restrict__ A0 = (const float4*)(W_ih + r0 * D);
        const float4* __restrict__ A1 = (const float4*)(W_ih + (r0 + 1) * D);
        const float4* __restrict__ x4 = (const float4*)x;
        #pragma unroll 4
        for (int it = 0; it < 32; ++it) {
            const int idx = it * 64 + lane;
            const float4 xv = x4[idx];
            acc0 += dot4(A0[idx], xv);
            acc1 += dot4(A1[idx], xv);
        }
        if (lane == 0) {  // tail float4 (idx 2048)
            const float4 xv = x4[2048];
            acc0 += dot4(A0[2048], xv);
            acc1 += dot4(A1[2048], xv);
        }
    }
    // ---- W_hh rows r0, r0+1 . h0  (H/4 = 1024 float4s per row) ----
    {
        const float4* __restrict__ B0 = (const float4*)(W_hh + r0 * H);
        const float4* __restrict__ B1 = (const float4*)(W_hh + (r0 + 1) * H);
        const float4* __restrict__ h4 = (const float4*)h0;
        #pragma unroll 4
        for (int it = 0; it < 16; ++it) {
            const int idx = it * 64 + lane;
            const float4 hv = h4[idx];
            acc0 += dot4(B0[idx], hv);
            acc1 += dot4(B1[idx], hv);
        }
    }

    acc0 = wave_reduce(acc0);
    acc1 = wave_reduce(acc1);

    __shared__ float gate[4][2];
    __shared__ int lastflag;
    if (lane == 0) {
        gate[g][0] = acc0 + b_ih[r0]     + b_hh[r0];
        gate[g][1] = acc1 + b_ih[r0 + 1] + b_hh[r0 + 1];
    }
    __syncthreads();

    if (threadIdx.x < 2) {
        const int t = threadIdx.x;
        const int j = j0 + t;
        const float ig = sigmoidf_(gate[0][t]);
        const float fg = sigmoidf_(gate[1][t]);
        const float gg = tanhf(gate[2][t]);
        const float og = sigmoidf_(gate[3][t]);
        const float c  = fg * c0[j] + ig * gg;
        h_ws[j] = og * tanhf(c);
    }

    // Release h_ws device-wide, then count finished blocks.
    __threadfence();
    if (threadIdx.x == 0)
        lastflag = (atomicAdd(counter, 1u) == (unsigned)(gridDim.x - 1));
    __syncthreads();
    if (!lastflag) return;
    __threadfence();  // acquire: see all blocks' h_ws stores

    // ---- MLP head (last block only): z = relu(W1@h+b1); out = sigmoid(W2@z+b2)
    __shared__ float z[MLP_HID];
    {
        const float4* __restrict__ h4 = (const float4*)h_ws;
        for (int r = g; r < MLP_HID; r += 4) {
            const float4* __restrict__ Wr = (const float4*)(W1 + (size_t)r * H);
            float acc = 0.0f;
            #pragma unroll 4
            for (int it = 0; it < 16; ++it) {
                const int idx = it * 64 + lane;
                acc += dot4(Wr[idx], h4[idx]);
            }
            acc = wave_reduce(acc);
            if (lane == 0)
                z[r] = fmaxf(acc + b1[r], 0.0f);
        }
    }
    __syncthreads();

    if (threadIdx.x < OUT_N) {
        float acc = b2[threadIdx.x];
        #pragma unroll
        for (int k = 0; k < MLP_HID; ++k)
            acc += W2[threadIdx.x * MLP_HID + k] * z[k];
        out[threadIdx.x] = sigmoidf_(acc);
    }
}

extern "C" void kernel_launch(void* const* d_in, const int* in_sizes, int n_in,
                              void* d_out, int out_size, void* d_ws, size_t ws_size,
                              hipStream_t stream) {
    const float* x    = (const float*)d_in[0];
    const float* h0   = (const float*)d_in[1];
    const float* c0   = (const float*)d_in[2];
    const float* W_ih = (const float*)d_in[3];
    const float* W_hh = (const float*)d_in[4];
    const float* b_ih = (const float*)d_in[5];
    const float* b_hh = (const float*)d_in[6];
    const float* W1   = (const float*)d_in[7];
    const float* b1   = (const float*)d_in[8];
    const float* W2   = (const float*)d_in[9];
    const float* b2   = (const float*)d_in[10];
    float* out = (float*)d_out;

    // ws layout: [0..3] counter, [256B ...] h (H floats, 16B-aligned)
    unsigned int* counter = (unsigned int*)d_ws;
    float* h_ws = (float*)((char*)d_ws + 256);

    (void)hipMemsetAsync(counter, 0, sizeof(unsigned int), stream);
    brain_fused_kernel<<<H / 2, 256, 0, stream>>>(
        x, h0, c0, W_ih, W_hh, b_ih, b_hh, W1, b1, W2, b2, out, counter, h_ws);
}

// Round 5
// 162.687 us; speedup vs baseline: 3.4315x; 3.4315x over previous
//
#include <hip/hip_runtime.h>
#include <hip/hip_bf16.h>

#define D 8196
#define H 4096
#define MLP_HID 32
#define OUT_N 130
#define ND4 2049   // D/4 float4s per W_ih row
#define NH4 1024   // H/4 float4s per W_hh row

__device__ __forceinline__ float sigmoidf_(float v) {
    return 1.0f / (1.0f + expf(-v));
}

__device__ __forceinline__ float dot4(float4 a, float4 b) {
    return a.x * b.x + a.y * b.y + a.z * b.z + a.w * b.w;
}

__device__ __forceinline__ float wave_reduce(float acc) {
    #pragma unroll
    for (int off = 32; off > 0; off >>= 1)
        acc += __shfl_down(acc, off);
    return acc;
}

// 2048 blocks x 256 threads, 3 blocks/CU (LDS-limited: 48 KB for x+h0).
// Block b owns hidden units j0=2b, j0+1. Wave g computes gate rows
// g*H+j0 and g*H+j0+1 SEQUENTIALLY (rows r, r+1 are contiguous in memory
// -> one long sequential HBM stream per wave; R3's interleaved 2-stream
// pairing collapsed BW to 9% of peak). x/h0 are staged in LDS once per
// block so the inner loop issues only weight loads.
__global__ __launch_bounds__(256, 3) void lstm_step_kernel(
    const float* __restrict__ x, const float* __restrict__ h0,
    const float* __restrict__ c0,
    const float* __restrict__ W_ih, const float* __restrict__ W_hh,
    const float* __restrict__ b_ih, const float* __restrict__ b_hh,
    float* __restrict__ h_out)
{
    __shared__ float4 xs[ND4];
    __shared__ float4 hs[NH4];
    __shared__ float gate[4][2];

    const int tid = threadIdx.x;
    {
        const float4* __restrict__ x4 = (const float4*)x;
        const float4* __restrict__ h4 = (const float4*)h0;
        for (int i = tid; i < ND4; i += 256) xs[i] = x4[i];
        for (int i = tid; i < NH4; i += 256) hs[i] = h4[i];
    }
    __syncthreads();

    const int g    = tid >> 6;   // gate 0..3 (i,f,g,o)
    const int lane = tid & 63;
    const int j0   = blockIdx.x * 2;

    #pragma unroll
    for (int rr = 0; rr < 2; ++rr) {
        const size_t r = (size_t)g * H + j0 + rr;
        float a = 0.0f;

        // ---- W_ih row r . x : 2049 float4s, sequential stream ----
        {
            const float4* __restrict__ A = (const float4*)(W_ih + r * D);
            #pragma unroll 8
            for (int it = 0; it < 32; ++it) {
                const int idx = it * 64 + lane;
                a += dot4(A[idx], xs[idx]);
            }
            if (lane == 0)
                a += dot4(A[2048], xs[2048]);
        }
        // ---- W_hh row r . h0 : 1024 float4s, continues the stream ----
        {
            const float4* __restrict__ B = (const float4*)(W_hh + r * H);
            #pragma unroll 8
            for (int it = 0; it < 16; ++it) {
                const int idx = it * 64 + lane;
                a += dot4(B[idx], hs[idx]);
            }
        }

        a = wave_reduce(a);
        if (lane == 0)
            gate[g][rr] = a + b_ih[r] + b_hh[r];
    }
    __syncthreads();

    if (tid < 2) {
        const int j = j0 + tid;
        const float ig = sigmoidf_(gate[0][tid]);
        const float fg = sigmoidf_(gate[1][tid]);
        const float gg = tanhf(gate[2][tid]);
        const float og = sigmoidf_(gate[3][tid]);
        const float c  = fg * c0[j] + ig * gg;
        h_out[j] = og * tanhf(c);
    }
}

// Single block: z = relu(W1 @ h + b1) (32 rows), out = sigmoid(W2 @ z + b2) (130)
__global__ __launch_bounds__(1024) void mlp_head_kernel(
    const float* __restrict__ h,
    const float* __restrict__ W1, const float* __restrict__ b1,
    const float* __restrict__ W2, const float* __restrict__ b2,
    float* __restrict__ out)
{
    __shared__ float z[MLP_HID];
    const int wave = threadIdx.x >> 6;  // 0..15
    const int lane = threadIdx.x & 63;

    for (int r = wave; r < MLP_HID; r += 16) {
        const float4* __restrict__ Wr = (const float4*)(W1 + (size_t)r * H);
        const float4* __restrict__ h4 = (const float4*)h;
        float acc = 0.0f;
        #pragma unroll 4
        for (int idx = lane; idx < H / 4; idx += 64)
            acc += dot4(Wr[idx], h4[idx]);
        acc = wave_reduce(acc);
        if (lane == 0)
            z[r] = fmaxf(acc + b1[r], 0.0f);
    }
    __syncthreads();

    const int t = threadIdx.x;
    if (t < OUT_N) {
        float acc = b2[t];
        #pragma unroll
        for (int k = 0; k < MLP_HID; ++k)
            acc += W2[t * MLP_HID + k] * z[k];
        out[t] = sigmoidf_(acc);
    }
}

extern "C" void kernel_launch(void* const* d_in, const int* in_sizes, int n_in,
                              void* d_out, int out_size, void* d_ws, size_t ws_size,
                              hipStream_t stream) {
    const float* x    = (const float*)d_in[0];
    const float* h0   = (const float*)d_in[1];
    const float* c0   = (const float*)d_in[2];
    const float* W_ih = (const float*)d_in[3];
    const float* W_hh = (const float*)d_in[4];
    const float* b_ih = (const float*)d_in[5];
    const float* b_hh = (const float*)d_in[6];
    const float* W1   = (const float*)d_in[7];
    const float* b1   = (const float*)d_in[8];
    const float* W2   = (const float*)d_in[9];
    const float* b2   = (const float*)d_in[10];
    float* out = (float*)d_out;

    float* h_ws = (float*)d_ws;  // H floats of scratch for the hidden state

    lstm_step_kernel<<<H / 2, 256, 0, stream>>>(x, h0, c0, W_ih, W_hh, b_ih, b_hh, h_ws);
    mlp_head_kernel<<<1, 1024, 0, stream>>>(h_ws, W1, b1, W2, b2, out);
}

// Round 6
// 153.085 us; speedup vs baseline: 3.6468x; 1.0627x over previous
//
#include <hip/hip_runtime.h>
#include <hip/hip_bf16.h>

#define D 8196
#define H 4096
#define MLP_HID 32
#define OUT_N 130
#define ND4 2049   // D/4 float4s per W_ih row (rounded up; D=8196 -> exactly 2049)
#define NH4 1024   // H/4 float4s per W_hh row

__device__ __forceinline__ float sigmoidf_(float v) {
    return 1.0f / (1.0f + expf(-v));
}

__device__ __forceinline__ float dot4(float4 a, float4 b) {
    return a.x * b.x + a.y * b.y + a.z * b.z + a.w * b.w;
}

__device__ __forceinline__ float wave_reduce(float acc) {
    #pragma unroll
    for (int off = 32; off > 0; off >>= 1)
        acc += __shfl_down(acc, off);
    return acc;
}

// 1024 blocks x 512 threads (8 waves), 4 blocks/CU (LDS = 32.8 KB for x only)
// -> 1024 resident blocks = grid: EXACTLY ONE dispatch round, zero tail.
// Block owns hidden units j0..j0+3. Wave w: gate g=w&3, unit pair p=w>>2;
// reads its 2 contiguous gate rows sequentially (one HBM stream per wave).
// x comes from LDS; h0 is read from L2 (16 KB, broadcast across waves).
__global__ __launch_bounds__(512, 8) void lstm_step_kernel(
    const float* __restrict__ x, const float* __restrict__ h0,
    const float* __restrict__ c0,
    const float* __restrict__ W_ih, const float* __restrict__ W_hh,
    const float* __restrict__ b_ih, const float* __restrict__ b_hh,
    float* __restrict__ h_out)
{
    __shared__ float4 xs[ND4];
    __shared__ float gate[4][4];

    const int tid = threadIdx.x;
    {
        const float4* __restrict__ x4 = (const float4*)x;
        for (int i = tid; i < ND4; i += 512) xs[i] = x4[i];
    }
    __syncthreads();

    const int w    = tid >> 6;   // wave 0..7
    const int lane = tid & 63;
    const int g    = w & 3;      // gate (i,f,g,o)
    const int p    = w >> 2;     // unit pair 0/1
    const int j0   = blockIdx.x * 4;

    #pragma unroll
    for (int rr = 0; rr < 2; ++rr) {
        const int u = 2 * p + rr;                 // unit within block 0..3
        const size_t r = (size_t)g * H + j0 + u;  // gate row
        float a = 0.0f;

        // ---- W_ih row r . x : 2049 float4s, one sequential stream ----
        {
            const float4* __restrict__ A = (const float4*)(W_ih + r * D);
            #pragma unroll 4
            for (int it = 0; it < 32; ++it) {
                const int idx = it * 64 + lane;
                a += dot4(A[idx], xs[idx]);
            }
            if (lane == 0)
                a += dot4(A[2048], xs[2048]);
        }
        // ---- W_hh row r . h0 : 1024 float4s, stream continues; h0 from L2 ----
        {
            const float4* __restrict__ B = (const float4*)(W_hh + r * H);
            const float4* __restrict__ h4 = (const float4*)h0;
            #pragma unroll 4
            for (int it = 0; it < 16; ++it) {
                const int idx = it * 64 + lane;
                a += dot4(B[idx], h4[idx]);
            }
        }

        a = wave_reduce(a);
        if (lane == 0)
            gate[g][u] = a + b_ih[r] + b_hh[r];
    }
    __syncthreads();

    if (tid < 4) {
        const int j = j0 + tid;
        const float ig = sigmoidf_(gate[0][tid]);
        const float fg = sigmoidf_(gate[1][tid]);
        const float gg = tanhf(gate[2][tid]);
        const float og = sigmoidf_(gate[3][tid]);
        const float c  = fg * c0[j] + ig * gg;
        h_out[j] = og * tanhf(c);
    }
}

// 32 blocks x 64 threads: block r computes z[r] = relu(W1[r,:] @ h + b1[r])
__global__ __launch_bounds__(64) void mlp_z_kernel(
    const float* __restrict__ h,
    const float* __restrict__ W1, const float* __restrict__ b1,
    float* __restrict__ z)
{
    const int r    = blockIdx.x;
    const int lane = threadIdx.x;
    const float4* __restrict__ Wr = (const float4*)(W1 + (size_t)r * H);
    const float4* __restrict__ h4 = (const float4*)h;
    float acc = 0.0f;
    #pragma unroll 4
    for (int it = 0; it < 16; ++it) {
        const int idx = it * 64 + lane;
        acc += dot4(Wr[idx], h4[idx]);
    }
    acc = wave_reduce(acc);
    if (lane == 0)
        z[r] = fmaxf(acc + b1[r], 0.0f);
}

// 1 block: out = sigmoid(W2 @ z + b2), 130 outputs
__global__ __launch_bounds__(192) void mlp_out_kernel(
    const float* __restrict__ z,
    const float* __restrict__ W2, const float* __restrict__ b2,
    float* __restrict__ out)
{
    __shared__ float zs[MLP_HID];
    if (threadIdx.x < MLP_HID) zs[threadIdx.x] = z[threadIdx.x];
    __syncthreads();
    const int t = threadIdx.x;
    if (t < OUT_N) {
        float acc = b2[t];
        #pragma unroll
        for (int k = 0; k < MLP_HID; ++k)
            acc += W2[t * MLP_HID + k] * zs[k];
        out[t] = sigmoidf_(acc);
    }
}

extern "C" void kernel_launch(void* const* d_in, const int* in_sizes, int n_in,
                              void* d_out, int out_size, void* d_ws, size_t ws_size,
                              hipStream_t stream) {
    const float* x    = (const float*)d_in[0];
    const float* h0   = (const float*)d_in[1];
    const float* c0   = (const float*)d_in[2];
    const float* W_ih = (const float*)d_in[3];
    const float* W_hh = (const float*)d_in[4];
    const float* b_ih = (const float*)d_in[5];
    const float* b_hh = (const float*)d_in[6];
    const float* W1   = (const float*)d_in[7];
    const float* b1   = (const float*)d_in[8];
    const float* W2   = (const float*)d_in[9];
    const float* b2   = (const float*)d_in[10];
    float* out = (float*)d_out;

    // ws layout: [0, 16KB) h, [16KB, 16KB+128) z
    float* h_ws = (float*)d_ws;
    float* z_ws = (float*)((char*)d_ws + 16384);

    lstm_step_kernel<<<H / 4, 512, 0, stream>>>(x, h0, c0, W_ih, W_hh, b_ih, b_hh, h_ws);
    mlp_z_kernel<<<MLP_HID, 64, 0, stream>>>(h_ws, W1, b1, z_ws);
    mlp_out_kernel<<<1, 192, 0, stream>>>(z_ws, W2, b2, out);
}